// Round 1
// baseline (248.318 us; speedup 1.0000x reference)
//
#include <hip/hip_runtime.h>

#define BATCH 4
#define SEQ   4096
#define CDIM  1024
#define HDIM  64

typedef __attribute__((ext_vector_type(8))) short bf16x8;
typedef __attribute__((ext_vector_type(4))) float f32x4;

// ws layout (in shorts):
//   wt [3][64][1024]   (W^T, bf16)        @ 0
//   q  [16384][64]     (bf16, row-major)  @ Q_OFF
//   k  [16384][64]     (bf16, row-major)  @ K_OFF
//   vt [4][64][4096]   (bf16, transposed) @ VT_OFF
#define WT_OFF 0
#define Q_OFF  (3 * HDIM * CDIM)
#define K_OFF  (Q_OFF + BATCH * SEQ * HDIM)
#define VT_OFF (K_OFF + BATCH * SEQ * HDIM)

static __device__ __forceinline__ short f2bf(float f) {
  union { float f; unsigned u; } a; a.f = f;
  unsigned r = a.u + 0x7fffu + ((a.u >> 16) & 1u);   // RNE
  return (short)(r >> 16);
}

static __device__ __forceinline__ bf16x8 ld8(const short* p) {
  return *(const bf16x8*)p;
}

// ---------------- kernel 0: W -> bf16, transposed to [h][c] ----------------
__global__ void wcvt_kernel(const float* __restrict__ wq, const float* __restrict__ wk,
                            const float* __restrict__ wv, short* __restrict__ wt) {
  int idx = blockIdx.x * 256 + threadIdx.x;   // 0 .. 3*65536-1
  int m = idx >> 16;
  int r = idx & 65535;
  int c = r >> 6, h = r & 63;
  const float* w = (m == 0) ? wq : (m == 1) ? wk : wv;
  wt[m * 65536 + h * 1024 + c] = f2bf(w[c * 64 + h]);
}

// ---------------- kernel 1: fused q/k/v projection ----------------
// one wave = 16 rows of x, computes all 192 outputs (q,k,v) via MFMA
__global__ __launch_bounds__(256) void proj_kernel(const float* __restrict__ x,
                                                   const short* __restrict__ wt,
                                                   short* __restrict__ ws) {
  int wave = blockIdx.x * 4 + (threadIdx.x >> 6);
  int lane = threadIdx.x & 63;
  int lr = lane & 15, lg = lane >> 4;
  int row0 = wave * 16;
  const float* xrow = x + (size_t)(row0 + lr) * CDIM + lg * 8;

  f32x4 acc[3][4] = {};
#pragma unroll 4
  for (int k0 = 0; k0 < CDIM; k0 += 32) {
    float4 f1 = *(const float4*)(xrow + k0);
    float4 f2 = *(const float4*)(xrow + k0 + 4);
    bf16x8 af;
    af[0] = f2bf(f1.x); af[1] = f2bf(f1.y); af[2] = f2bf(f1.z); af[3] = f2bf(f1.w);
    af[4] = f2bf(f2.x); af[5] = f2bf(f2.y); af[6] = f2bf(f2.z); af[7] = f2bf(f2.w);
#pragma unroll
    for (int m = 0; m < 3; ++m)
#pragma unroll
      for (int hc = 0; hc < 4; ++hc) {
        bf16x8 bf = ld8(wt + m * 65536 + (hc * 16 + lr) * 1024 + k0 + lg * 8);
        acc[m][hc] = __builtin_amdgcn_mfma_f32_16x16x32_bf16(af, bf, acc[m][hc], 0, 0, 0);
      }
  }

  short* qs  = ws + Q_OFF;
  short* kst = ws + K_OFF;
  short* vts = ws + VT_OFF;
  int b = row0 >> 12, t0 = row0 & (SEQ - 1);
#pragma unroll
  for (int hc = 0; hc < 4; ++hc)
#pragma unroll
    for (int reg = 0; reg < 4; ++reg) {
      int i = lg * 4 + reg, h = hc * 16 + lr;
      qs [(row0 + i) * 64 + h] = f2bf(acc[0][hc][reg]);
      kst[(row0 + i) * 64 + h] = f2bf(acc[1][hc][reg]);
      vts[(b * 64 + h) * SEQ + t0 + i] = f2bf(acc[2][hc][reg]);  // v transposed
    }
}

// ---------------- kernel 2: causal flash attention ----------------
// one wave = 16 q rows; KVBLK=32; online softmax; P via LDS reshape
__global__ __launch_bounds__(256) void attn_kernel(const short* __restrict__ ws,
                                                   float* __restrict__ out) {
  __shared__ short plds[4][16 * 32];
  int widx = threadIdx.x >> 6, lane = threadIdx.x & 63;
  int wave = blockIdx.x * 4 + widx;          // 0..1023
  int b = wave >> 8, qt = wave & 255;
  int lr = lane & 15, lg = lane >> 4;

  const short* qs  = ws + Q_OFF;
  const short* kst = ws + K_OFF;
  const short* vts = ws + VT_OFF;

  int qbase = b * SEQ + qt * 16;
  bf16x8 qf0 = ld8(qs + (qbase + lr) * 64 + lg * 8);
  bf16x8 qf1 = ld8(qs + (qbase + lr) * 64 + 32 + lg * 8);

  f32x4 o[4] = {};
  float m_run[4] = {-1e30f, -1e30f, -1e30f, -1e30f};
  float l_run[4] = {};
  short* myp = plds[widx];
  int nkv = qt / 2 + 1;

  for (int kvb = 0; kvb < nkv; ++kvb) {
    int kv0 = kvb * 32;
    const short* kb = kst + (b * SEQ + kv0) * 64;

    f32x4 s0 = {}, s1 = {};
    s0 = __builtin_amdgcn_mfma_f32_16x16x32_bf16(qf0, ld8(kb + lr * 64 + lg * 8), s0, 0, 0, 0);
    s0 = __builtin_amdgcn_mfma_f32_16x16x32_bf16(qf1, ld8(kb + lr * 64 + 32 + lg * 8), s0, 0, 0, 0);
    s1 = __builtin_amdgcn_mfma_f32_16x16x32_bf16(qf0, ld8(kb + (16 + lr) * 64 + lg * 8), s1, 0, 0, 0);
    s1 = __builtin_amdgcn_mfma_f32_16x16x32_bf16(qf1, ld8(kb + (16 + lr) * 64 + 32 + lg * 8), s1, 0, 0, 0);

    bool last = (kvb == nkv - 1);
    float alpha[4], p0[4], p1[4];
#pragma unroll
    for (int reg = 0; reg < 4; ++reg) {
      float v0 = s0[reg] * 0.125f, v1 = s1[reg] * 0.125f;
      if (last) {
        int ig = qt * 16 + lg * 4 + reg;       // global q row within batch
        if (kv0 + lr > ig)      v0 = -1e30f;   // causal mask
        if (kv0 + 16 + lr > ig) v1 = -1e30f;
      }
      float mb = fmaxf(v0, v1);
      mb = fmaxf(mb, __shfl_xor(mb, 1));
      mb = fmaxf(mb, __shfl_xor(mb, 2));
      mb = fmaxf(mb, __shfl_xor(mb, 4));
      mb = fmaxf(mb, __shfl_xor(mb, 8));
      float mn = fmaxf(m_run[reg], mb);
      alpha[reg] = __expf(m_run[reg] - mn);
      m_run[reg] = mn;
      float e0 = __expf(v0 - mn), e1 = __expf(v1 - mn);
      float rs = e0 + e1;
      rs += __shfl_xor(rs, 1);
      rs += __shfl_xor(rs, 2);
      rs += __shfl_xor(rs, 4);
      rs += __shfl_xor(rs, 8);
      l_run[reg] = l_run[reg] * alpha[reg] + rs;
      p0[reg] = e0; p1[reg] = e1;
    }
#pragma unroll
    for (int hc = 0; hc < 4; ++hc)
#pragma unroll
      for (int reg = 0; reg < 4; ++reg) o[hc][reg] *= alpha[reg];

    // P (f32, S-layout) -> LDS [16 rows][32 cols] bf16, then re-read as A-frag
#pragma unroll
    for (int reg = 0; reg < 4; ++reg) {
      myp[(lg * 4 + reg) * 32 + lr]      = f2bf(p0[reg]);
      myp[(lg * 4 + reg) * 32 + 16 + lr] = f2bf(p1[reg]);
    }
    asm volatile("s_waitcnt lgkmcnt(0)" ::: "memory");
    bf16x8 pf = ld8(myp + lr * 32 + lg * 8);

    const short* vb = vts + b * 64 * SEQ + kv0;
#pragma unroll
    for (int hc = 0; hc < 4; ++hc) {
      bf16x8 vf = ld8(vb + (hc * 16 + lr) * SEQ + lg * 8);
      o[hc] = __builtin_amdgcn_mfma_f32_16x16x32_bf16(pf, vf, o[hc], 0, 0, 0);
    }
  }

#pragma unroll
  for (int reg = 0; reg < 4; ++reg) {
    float inv = 1.0f / l_run[reg];
#pragma unroll
    for (int hc = 0; hc < 4; ++hc)
      out[(qbase + lg * 4 + reg) * 64 + hc * 16 + lr] = o[hc][reg] * inv;
  }
}

extern "C" void kernel_launch(void* const* d_in, const int* in_sizes, int n_in,
                              void* d_out, int out_size, void* d_ws, size_t ws_size,
                              hipStream_t stream) {
  const float* x  = (const float*)d_in[0];
  const float* wq = (const float*)d_in[1];
  const float* wk = (const float*)d_in[2];
  const float* wv = (const float*)d_in[3];
  short* ws = (short*)d_ws;
  float* out = (float*)d_out;

  wcvt_kernel<<<dim3(768), dim3(256), 0, stream>>>(wq, wk, wv, ws + WT_OFF);
  proj_kernel<<<dim3(256), dim3(256), 0, stream>>>(x, ws + WT_OFF, ws);
  attn_kernel<<<dim3(256), dim3(256), 0, stream>>>(ws, out);
}

// Round 2
// 145.629 us; speedup vs baseline: 1.7051x; 1.7051x over previous
//
#include <hip/hip_runtime.h>

#define BATCH 4
#define SEQ   4096
#define CDIM  1024
#define HDIM  64

typedef __attribute__((ext_vector_type(8))) short bf16x8;
typedef __attribute__((ext_vector_type(4))) float f32x4;

// ws layout (in shorts):
//   wt [3][64][1024]   (W^T, bf16)        @ 0
//   q  [16384][64]     (bf16, row-major)  @ Q_OFF
//   k  [16384][64]     (bf16, row-major)  @ K_OFF
//   vt [4][64][4096]   (bf16, transposed) @ VT_OFF
#define WT_OFF 0
#define Q_OFF  (3 * HDIM * CDIM)
#define K_OFF  (Q_OFF + BATCH * SEQ * HDIM)
#define VT_OFF (K_OFF + BATCH * SEQ * HDIM)

static __device__ __forceinline__ short f2bf(float f) {
  union { float f; unsigned u; } a; a.f = f;
  unsigned r = a.u + 0x7fffu + ((a.u >> 16) & 1u);   // RNE
  return (short)(r >> 16);
}

static __device__ __forceinline__ bf16x8 ld8(const short* p) {
  return *(const bf16x8*)p;
}

// ---------------- kernel 0: W -> bf16, transposed to [h][c] ----------------
__global__ void wcvt_kernel(const float* __restrict__ wq, const float* __restrict__ wk,
                            const float* __restrict__ wv, short* __restrict__ wt) {
  int idx = blockIdx.x * 256 + threadIdx.x;   // 0 .. 3*65536-1
  int m = idx >> 16;
  int r = idx & 65535;
  int c = r >> 6, h = r & 63;
  const float* w = (m == 0) ? wq : (m == 1) ? wk : wv;
  wt[m * 65536 + h * 1024 + c] = f2bf(w[c * 64 + h]);
}

// ---------------- kernel 1: fused q/k/v projection ----------------
// one BLOCK = 16 rows of x; 4 waves split C (256 each); merge partials in LDS
__global__ __launch_bounds__(256) void proj_kernel(const float* __restrict__ x,
                                                   const short* __restrict__ wt,
                                                   short* __restrict__ ws) {
  __shared__ float part[4][12][4][64];   // [wave][m*4+hc][reg][lane] = 48KB
  int widx = threadIdx.x >> 6, lane = threadIdx.x & 63;
  int lr = lane & 15, lg = lane >> 4;
  int row0 = blockIdx.x * 16;
  const float* xrow = x + (size_t)(row0 + lr) * CDIM + widx * 256 + lg * 8;
  const short* wbase = wt + widx * 256 + lg * 8;

  f32x4 acc[3][4] = {};
#pragma unroll 2
  for (int k0 = 0; k0 < 256; k0 += 32) {
    float4 f1 = *(const float4*)(xrow + k0);
    float4 f2 = *(const float4*)(xrow + k0 + 4);
    bf16x8 af;
    af[0] = f2bf(f1.x); af[1] = f2bf(f1.y); af[2] = f2bf(f1.z); af[3] = f2bf(f1.w);
    af[4] = f2bf(f2.x); af[5] = f2bf(f2.y); af[6] = f2bf(f2.z); af[7] = f2bf(f2.w);
#pragma unroll
    for (int m = 0; m < 3; ++m)
#pragma unroll
      for (int hc = 0; hc < 4; ++hc) {
        bf16x8 bf = ld8(wbase + m * 65536 + (hc * 16 + lr) * 1024 + k0);
        acc[m][hc] = __builtin_amdgcn_mfma_f32_16x16x32_bf16(af, bf, acc[m][hc], 0, 0, 0);
      }
  }

#pragma unroll
  for (int m = 0; m < 3; ++m)
#pragma unroll
    for (int hc = 0; hc < 4; ++hc)
#pragma unroll
      for (int reg = 0; reg < 4; ++reg)
        part[widx][m * 4 + hc][reg][lane] = acc[m][hc][reg];
  __syncthreads();

  short* qs  = ws + Q_OFF;
  short* kst = ws + K_OFF;
  short* vts = ws + VT_OFF;
  int b = row0 >> 12, t0 = row0 & (SEQ - 1);
#pragma unroll
  for (int pp = 0; pp < 3; ++pp) {
    int p = widx * 3 + pp;
    int m = p >> 2, hc = p & 3;
#pragma unroll
    for (int reg = 0; reg < 4; ++reg) {
      float s = part[0][p][reg][lane] + part[1][p][reg][lane] +
                part[2][p][reg][lane] + part[3][p][reg][lane];
      int i = lg * 4 + reg, h = hc * 16 + lr;
      short bv = f2bf(s);
      if (m == 0)      qs [(row0 + i) * 64 + h] = bv;
      else if (m == 1) kst[(row0 + i) * 64 + h] = bv;
      else             vts[(b * 64 + h) * SEQ + t0 + i] = bv;   // v transposed
    }
  }
}

// ---------------- kernel 2: causal flash attention ----------------
// one BLOCK = 16 q rows; 4 waves split KV strided; LDS log-sum-exp merge
__global__ __launch_bounds__(256) void attn_kernel(const short* __restrict__ ws,
                                                   float* __restrict__ out) {
  __shared__ float p_o[4][4][4][64];    // [wave][hc][reg][lane] 16KB
  __shared__ float p_ml[4][2][4][64];   // [wave][m/l][reg][lane] 8KB
  __shared__ short plds[4][16 * 32];    // 4KB
  int widx = threadIdx.x >> 6, lane = threadIdx.x & 63;
  int lr = lane & 15, lg = lane >> 4;
  int g = blockIdx.x;
  int b = g >> 8, i = g & 255;
  // per-CU work balancing: the 4 co-resident blocks on a CU get qt values
  // summing to a constant (514) regardless of i
  int qt;
  if (b == 0)      qt = i;
  else if (b == 1) qt = 255 - i;
  else if (b == 2) qt = (i + 128) & 255;
  else             qt = 255 - ((i + 128) & 255);

  const short* qs  = ws + Q_OFF;
  const short* kst = ws + K_OFF;
  const short* vts = ws + VT_OFF;

  int qbase = b * SEQ + qt * 16;
  bf16x8 qf0 = ld8(qs + (qbase + lr) * 64 + lg * 8);
  bf16x8 qf1 = ld8(qs + (qbase + lr) * 64 + 32 + lg * 8);

  f32x4 o[4] = {};
  float m_run[4] = {-1e30f, -1e30f, -1e30f, -1e30f};
  float l_run[4] = {};
  short* myp = plds[widx];
  int nkv = qt / 2 + 1;

  for (int kvb = widx; kvb < nkv; kvb += 4) {
    int kv0 = kvb * 32;
    const short* kb = kst + (b * SEQ + kv0) * 64;

    f32x4 s0 = {}, s1 = {};
    s0 = __builtin_amdgcn_mfma_f32_16x16x32_bf16(qf0, ld8(kb + lr * 64 + lg * 8), s0, 0, 0, 0);
    s0 = __builtin_amdgcn_mfma_f32_16x16x32_bf16(qf1, ld8(kb + lr * 64 + 32 + lg * 8), s0, 0, 0, 0);
    s1 = __builtin_amdgcn_mfma_f32_16x16x32_bf16(qf0, ld8(kb + (16 + lr) * 64 + lg * 8), s1, 0, 0, 0);
    s1 = __builtin_amdgcn_mfma_f32_16x16x32_bf16(qf1, ld8(kb + (16 + lr) * 64 + 32 + lg * 8), s1, 0, 0, 0);

    bool last = (kvb == nkv - 1);
    float alpha[4], p0[4], p1[4];
#pragma unroll
    for (int reg = 0; reg < 4; ++reg) {
      float v0 = s0[reg] * 0.125f, v1 = s1[reg] * 0.125f;
      if (last) {
        int ig = qt * 16 + lg * 4 + reg;       // global q row within batch
        if (kv0 + lr > ig)      v0 = -1e30f;   // causal mask
        if (kv0 + 16 + lr > ig) v1 = -1e30f;
      }
      float mb = fmaxf(v0, v1);
      mb = fmaxf(mb, __shfl_xor(mb, 1));
      mb = fmaxf(mb, __shfl_xor(mb, 2));
      mb = fmaxf(mb, __shfl_xor(mb, 4));
      mb = fmaxf(mb, __shfl_xor(mb, 8));
      float mn = fmaxf(m_run[reg], mb);
      alpha[reg] = __expf(m_run[reg] - mn);
      m_run[reg] = mn;
      float e0 = __expf(v0 - mn), e1 = __expf(v1 - mn);
      float rs = e0 + e1;
      rs += __shfl_xor(rs, 1);
      rs += __shfl_xor(rs, 2);
      rs += __shfl_xor(rs, 4);
      rs += __shfl_xor(rs, 8);
      l_run[reg] = l_run[reg] * alpha[reg] + rs;
      p0[reg] = e0; p1[reg] = e1;
    }
#pragma unroll
    for (int hc = 0; hc < 4; ++hc)
#pragma unroll
      for (int reg = 0; reg < 4; ++reg) o[hc][reg] *= alpha[reg];

    // P (f32, S-layout) -> LDS [16 rows][32 cols] bf16, then re-read as A-frag
#pragma unroll
    for (int reg = 0; reg < 4; ++reg) {
      myp[(lg * 4 + reg) * 32 + lr]      = f2bf(p0[reg]);
      myp[(lg * 4 + reg) * 32 + 16 + lr] = f2bf(p1[reg]);
    }
    asm volatile("s_waitcnt lgkmcnt(0)" ::: "memory");
    bf16x8 pf = ld8(myp + lr * 32 + lg * 8);

    const short* vb = vts + b * 64 * SEQ + kv0;
#pragma unroll
    for (int hc = 0; hc < 4; ++hc) {
      bf16x8 vf = ld8(vb + (hc * 16 + lr) * SEQ + lg * 8);
      o[hc] = __builtin_amdgcn_mfma_f32_16x16x32_bf16(pf, vf, o[hc], 0, 0, 0);
    }
  }

  // publish partials (even if this wave did zero kv blocks)
#pragma unroll
  for (int hc = 0; hc < 4; ++hc)
#pragma unroll
    for (int reg = 0; reg < 4; ++reg)
      p_o[widx][hc][reg][lane] = o[hc][reg];
#pragma unroll
  for (int reg = 0; reg < 4; ++reg) {
    p_ml[widx][0][reg][lane] = m_run[reg];
    p_ml[widx][1][reg][lane] = l_run[reg];
  }
  __syncthreads();

  if (widx == 0) {
#pragma unroll
    for (int reg = 0; reg < 4; ++reg) {
      float M = p_ml[0][0][reg][lane];
      M = fmaxf(M, p_ml[1][0][reg][lane]);
      M = fmaxf(M, p_ml[2][0][reg][lane]);
      M = fmaxf(M, p_ml[3][0][reg][lane]);
      float sc[4], lsum = 0.f;
#pragma unroll
      for (int w = 0; w < 4; ++w) {
        sc[w] = __expf(p_ml[w][0][reg][lane] - M);
        lsum += p_ml[w][1][reg][lane] * sc[w];
      }
      float inv = 1.0f / lsum;
#pragma unroll
      for (int hc = 0; hc < 4; ++hc) {
        float s = 0.f;
#pragma unroll
        for (int w = 0; w < 4; ++w) s += p_o[w][hc][reg][lane] * sc[w];
        out[(qbase + lg * 4 + reg) * 64 + hc * 16 + lr] = s * inv;
      }
    }
  }
}

extern "C" void kernel_launch(void* const* d_in, const int* in_sizes, int n_in,
                              void* d_out, int out_size, void* d_ws, size_t ws_size,
                              hipStream_t stream) {
  const float* x  = (const float*)d_in[0];
  const float* wq = (const float*)d_in[1];
  const float* wk = (const float*)d_in[2];
  const float* wv = (const float*)d_in[3];
  short* ws = (short*)d_ws;
  float* out = (float*)d_out;

  wcvt_kernel<<<dim3(768), dim3(256), 0, stream>>>(wq, wk, wv, ws + WT_OFF);
  proj_kernel<<<dim3(1024), dim3(256), 0, stream>>>(x, ws + WT_OFF, ws);
  attn_kernel<<<dim3(1024), dim3(256), 0, stream>>>(ws, out);
}

// Round 3
// 123.267 us; speedup vs baseline: 2.0145x; 1.1814x over previous
//
#include <hip/hip_runtime.h>

#define BATCH 4
#define SEQ   4096
#define CDIM  1024
#define HDIM  64

typedef __attribute__((ext_vector_type(8))) short bf16x8;
typedef __attribute__((ext_vector_type(4))) float f32x4;

// ws layout (in shorts):
//   wt2 [32 k0g][12 p=m*4+hc][64 lane][8]  (bf16, MFMA-fragment order) @ 0
//   q   [16384][64]   (bf16, row-major)   @ Q_OFF
//   k   [16384][64]   (bf16, row-major)   @ K_OFF
//   vt  [4][64][4096] (bf16, transposed)  @ VT_OFF
#define WT_OFF 0
#define Q_OFF  (3 * HDIM * CDIM)
#define K_OFF  (Q_OFF + BATCH * SEQ * HDIM)
#define VT_OFF (K_OFF + BATCH * SEQ * HDIM)

static __device__ __forceinline__ short f2bf(float f) {
  union { float f; unsigned u; } a; a.f = f;
  unsigned r = a.u + 0x7fffu + ((a.u >> 16) & 1u);   // RNE
  return (short)(r >> 16);
}

static __device__ __forceinline__ bf16x8 ld8(const short* p) {
  return *(const bf16x8*)p;
}

// ---------------- kernel 0: W -> bf16, MFMA-fragment order ----------------
// dst[((k0g*12 + m*4 + hc)*64 + lr*4 + lg)*8 + j] = W_m[c][h],
//   c = k0g*32 + lg*8 + j, h = hc*16 + lr
__global__ void wcvt_kernel(const float* __restrict__ wq, const float* __restrict__ wk,
                            const float* __restrict__ wv, short* __restrict__ wt2) {
  int idx = blockIdx.x * 256 + threadIdx.x;   // 0 .. 3*65536-1
  int m = idx >> 16;
  int f = idx & 65535;
  int k0g = f >> 11, hc = (f >> 9) & 3, lr = (f >> 5) & 15, lg = (f >> 3) & 3, j = f & 7;
  int c = k0g * 32 + lg * 8 + j, h = hc * 16 + lr;
  const float* w = (m == 0) ? wq : (m == 1) ? wk : wv;
  wt2[((k0g * 12 + m * 4 + hc) * 64 + lr * 4 + lg) * 8 + j] = f2bf(w[c * 64 + h]);
}

// ---------------- kernel 1: fused q/k/v projection ----------------
// block = 32 rows, 8 waves. wave w: rows (w>>2)*16, hc = w&3, all 3 m's.
// x staged once per block in LDS (bf16, fragment order), double-buffered.
__global__ __launch_bounds__(512) void proj_kernel(const float* __restrict__ x,
                                                   const short* __restrict__ wt2,
                                                   short* __restrict__ ws) {
  __shared__ short xs[2][1024];          // [buf][rbh*512 + lr*32 + lg*8 + j]
  __shared__ short vt_lds[8][16][24];    // per-wave v transpose tile

  int tid = threadIdx.x;
  int widx = tid >> 6, lane = tid & 63;
  int lr = lane & 15, lg = lane >> 4;
  int row0 = blockIdx.x * 32;
  int rbh = widx >> 2;       // row half (0/1)
  int hcw = widx & 3;        // this wave's hc

  // staging thread mapping: 32 rows x 16 float2-chunks
  int srow = tid >> 4, sc2 = tid & 15;
  const float* xsrc = x + (size_t)(row0 + srow) * CDIM + sc2 * 2;
  int sdst = (srow >> 4) * 512 + (srow & 15) * 32 + (sc2 >> 2) * 8 + (sc2 & 3) * 2;

  const short* xrd  = &xs[0][0] + rbh * 512 + (lr * 4 + lg) * 8;
  const short* bptr = wt2 + (hcw * 64 + lr * 4 + lg) * 8;

  f32x4 acc[3] = {};

#define LDX(K)  (*(const float2*)(xsrc + (K) * 32))
#define STAGE(A, BUF) do {                                                   \
    unsigned u_ = (unsigned)(unsigned short)f2bf((A).x) |                    \
                  ((unsigned)(unsigned short)f2bf((A).y) << 16);             \
    *(unsigned*)(&xs[(BUF)][sdst]) = u_;                                     \
  } while (0)
#define COMPUTE(BUF, K) do {                                                 \
    bf16x8 af_ = *(const bf16x8*)(xrd + (BUF) * 1024);                       \
    const short* bk_ = bptr + (K) * (12 * 512);                              \
    _Pragma("unroll")                                                        \
    for (int pp = 0; pp < 3; ++pp) {                                         \
      bf16x8 bf_ = ld8(bk_ + pp * 2048);                                     \
      acc[pp] = __builtin_amdgcn_mfma_f32_16x16x32_bf16(af_, bf_, acc[pp], 0, 0, 0); \
    }                                                                        \
  } while (0)

  float2 a1 = LDX(1);
  { float2 a0 = LDX(0); STAGE(a0, 0); }
  __syncthreads();

  for (int k = 0; k < 32; k += 2) {
    float2 an0 = {0.f, 0.f}, an1 = {0.f, 0.f};
    if (k + 2 < 32) an0 = LDX(k + 2);
    COMPUTE(0, k);
    STAGE(a1, 1);
    __syncthreads();
    if (k + 2 < 32) an1 = LDX(k + 3);
    COMPUTE(1, k + 1);
    if (k + 2 < 32) STAGE(an0, 0);
    __syncthreads();
    a1 = an1;
  }

  // ---- stores ----
  short* qs  = ws + Q_OFF;
  short* kst = ws + K_OFF;
  short* vts = ws + VT_OFF;
  int rbase = row0 + rbh * 16;
#pragma unroll
  for (int reg = 0; reg < 4; ++reg) {
    int t = rbase + lg * 4 + reg;
    qs [t * 64 + hcw * 16 + lr] = f2bf(acc[0][reg]);
    kst[t * 64 + hcw * 16 + lr] = f2bf(acc[1][reg]);
    vt_lds[widx][lr][lg * 4 + reg] = f2bf(acc[2][reg]);   // [h16][t16]
  }
  // per-wave transpose read (compiler inserts lgkmcnt for LDS dep)
  if (lane < 32) {
    int hl = lane >> 1, tf = (lane & 1) * 8;
    bf16x8 vv = *(const bf16x8*)(&vt_lds[widx][hl][tf]);
    int bb = rbase >> 12, tt0 = rbase & (SEQ - 1);
    *(bf16x8*)(vts + (size_t)(bb * 64 + hcw * 16 + hl) * SEQ + tt0 + tf) = vv;
  }
}

// ---------------- kernel 2: causal flash attention ----------------
// block = 1 q-tile (16 rows), 8 waves split KV 8-way, KVBLK=64; LSE merge.
__global__ __launch_bounds__(512) void attn_kernel(const short* __restrict__ ws,
                                                   float* __restrict__ out) {
  __shared__ float p_o[8][4][4][64];    // 32KB
  __shared__ float p_ml[8][2][4][64];   // 8KB
  __shared__ short plds[8][16][72];     // 18KB (stride 144B, 16B-aligned rows)

  int widx = threadIdx.x >> 6, lane = threadIdx.x & 63;
  int lr = lane & 15, lg = lane >> 4;
  int g = blockIdx.x;
  int b = g >> 8, qt = 255 - (g & 255);   // heavy-first dispatch order

  const short* qs  = ws + Q_OFF;
  const short* kst = ws + K_OFF;
  const short* vts = ws + VT_OFF;

  int qbase = b * SEQ + qt * 16;
  bf16x8 qf0 = ld8(qs + (qbase + lr) * 64 + lg * 8);
  bf16x8 qf1 = ld8(qs + (qbase + lr) * 64 + 32 + lg * 8);

  f32x4 o[4] = {};
  float m_run[4] = {-1e30f, -1e30f, -1e30f, -1e30f};
  float l_run[4] = {};
  short* myp = &plds[widx][0][0];
  int nkv = (qt >> 2) + 1;   // # of 64-wide kv blocks

  for (int kvb = widx; kvb < nkv; kvb += 8) {
    int kv0 = kvb * 64;
    const short* kb = kst + (b * SEQ + kv0) * 64;

    f32x4 s[4] = {};
#pragma unroll
    for (int st = 0; st < 4; ++st) {
      s[st] = __builtin_amdgcn_mfma_f32_16x16x32_bf16(qf0, ld8(kb + (st * 16 + lr) * 64 + lg * 8), s[st], 0, 0, 0);
      s[st] = __builtin_amdgcn_mfma_f32_16x16x32_bf16(qf1, ld8(kb + (st * 16 + lr) * 64 + 32 + lg * 8), s[st], 0, 0, 0);
    }

    bool last = (kvb == nkv - 1);
    float e[4][4], alpha[4];
#pragma unroll
    for (int reg = 0; reg < 4; ++reg) {
      float v[4];
#pragma unroll
      for (int st = 0; st < 4; ++st) v[st] = s[st][reg] * 0.125f;
      if (last) {
        int ig = qt * 16 + lg * 4 + reg;
#pragma unroll
        for (int st = 0; st < 4; ++st)
          if (kv0 + st * 16 + lr > ig) v[st] = -1e30f;
      }
      float mb = fmaxf(fmaxf(v[0], v[1]), fmaxf(v[2], v[3]));
      mb = fmaxf(mb, __shfl_xor(mb, 1));
      mb = fmaxf(mb, __shfl_xor(mb, 2));
      mb = fmaxf(mb, __shfl_xor(mb, 4));
      mb = fmaxf(mb, __shfl_xor(mb, 8));
      float mn = fmaxf(m_run[reg], mb);
      alpha[reg] = __expf(m_run[reg] - mn);
      m_run[reg] = mn;
      float rs = 0.f;
#pragma unroll
      for (int st = 0; st < 4; ++st) { e[st][reg] = __expf(v[st] - mn); rs += e[st][reg]; }
      rs += __shfl_xor(rs, 1);
      rs += __shfl_xor(rs, 2);
      rs += __shfl_xor(rs, 4);
      rs += __shfl_xor(rs, 8);
      l_run[reg] = l_run[reg] * alpha[reg] + rs;
    }
#pragma unroll
    for (int hc = 0; hc < 4; ++hc)
#pragma unroll
      for (int reg = 0; reg < 4; ++reg) o[hc][reg] *= alpha[reg];

    // P -> LDS [16 rows][64 cols] bf16
#pragma unroll
    for (int reg = 0; reg < 4; ++reg)
#pragma unroll
      for (int st = 0; st < 4; ++st)
        myp[(lg * 4 + reg) * 72 + st * 16 + lr] = f2bf(e[st][reg]);
    asm volatile("s_waitcnt lgkmcnt(0)" ::: "memory");
    bf16x8 pf0 = ld8(myp + lr * 72 + lg * 8);
    bf16x8 pf1 = ld8(myp + lr * 72 + 32 + lg * 8);

    const short* vb = vts + b * 64 * SEQ + kv0;
#pragma unroll
    for (int hc = 0; hc < 4; ++hc) {
      o[hc] = __builtin_amdgcn_mfma_f32_16x16x32_bf16(pf0, ld8(vb + (hc * 16 + lr) * SEQ + lg * 8), o[hc], 0, 0, 0);
      o[hc] = __builtin_amdgcn_mfma_f32_16x16x32_bf16(pf1, ld8(vb + (hc * 16 + lr) * SEQ + 32 + lg * 8), o[hc], 0, 0, 0);
    }
  }

  // publish partials
#pragma unroll
  for (int hc = 0; hc < 4; ++hc)
#pragma unroll
    for (int reg = 0; reg < 4; ++reg)
      p_o[widx][hc][reg][lane] = o[hc][reg];
#pragma unroll
  for (int reg = 0; reg < 4; ++reg) {
    p_ml[widx][0][reg][lane] = m_run[reg];
    p_ml[widx][1][reg][lane] = l_run[reg];
  }
  __syncthreads();

  // merge: wave w (<4) handles reg = w
  if (widx < 4) {
    int reg = widx;
    float M = -1e30f;
#pragma unroll
    for (int w = 0; w < 8; ++w) M = fmaxf(M, p_ml[w][0][reg][lane]);
    float sc[8], lsum = 0.f;
#pragma unroll
    for (int w = 0; w < 8; ++w) {
      sc[w] = __expf(p_ml[w][0][reg][lane] - M);
      lsum += p_ml[w][1][reg][lane] * sc[w];
    }
    float inv = 1.0f / lsum;
#pragma unroll
    for (int hc = 0; hc < 4; ++hc) {
      float s = 0.f;
#pragma unroll
      for (int w = 0; w < 8; ++w) s += p_o[w][hc][reg][lane] * sc[w];
      out[(qbase + lg * 4 + reg) * 64 + hc * 16 + lr] = s * inv;
    }
  }
}

extern "C" void kernel_launch(void* const* d_in, const int* in_sizes, int n_in,
                              void* d_out, int out_size, void* d_ws, size_t ws_size,
                              hipStream_t stream) {
  const float* x  = (const float*)d_in[0];
  const float* wq = (const float*)d_in[1];
  const float* wk = (const float*)d_in[2];
  const float* wv = (const float*)d_in[3];
  short* ws = (short*)d_ws;
  float* out = (float*)d_out;

  wcvt_kernel<<<dim3(768), dim3(256), 0, stream>>>(wq, wk, wv, ws + WT_OFF);
  proj_kernel<<<dim3(512), dim3(512), 0, stream>>>(x, ws + WT_OFF, ws);
  attn_kernel<<<dim3(1024), dim3(512), 0, stream>>>(ws, out);
}